// Round 9
// baseline (1399.338 us; speedup 1.0000x reference)
//
#include <hip/hip_runtime.h>
#include <cmath>

#define N_NODES   100000
#define N_EDGES   1600000
#define N_FEATS   128
#define HIDDEN    64
#define N_CLASSES 40
#define N_LAYERS  8
#define ALPHA     0.1f
#define LAMDA     0.5f

#define SCAN_ITEMS 8
#define SCAN_BLK   256
#define SCAN_TILE  (SCAN_ITEMS * SCAN_BLK)                  // 2048
#define SCAN_NBLK  ((N_NODES + SCAN_TILE - 1) / SCAN_TILE)  // 49

#define FILL_RANGES 8
#define RANGE_SIZE  ((N_NODES + FILL_RANGES - 1) / FILL_RANGES)  // 12500
#define FILL_BLOCKS 1024

// feature chunking: h buffers stored [CHUNKS][N_NODES][CF] bf16
#define CHUNKS 4
#define CF     16
#define SPMM_BPC ((N_NODES + 3) / 4)   // blocks per chunk (4 nodes/block) = 25000

typedef unsigned short ushortT;
typedef unsigned int   uintT;

__device__ __forceinline__ float bf2f(ushortT u) {
    return __uint_as_float(((uintT)u) << 16);
}
__device__ __forceinline__ ushortT f2bf(float f) {
    uintT x = __float_as_uint(f);
    return (ushortT)((x + 0x7FFFu + ((x >> 16) & 1u)) >> 16);   // RNE
}
__device__ __forceinline__ size_t chunked_off(int v, int c) {
    return ((size_t)(c >> 4) * N_NODES + v) * CF + (c & 15);
}

// ---------------- CSR build ----------------

__global__ __launch_bounds__(256) void k_zero_deg(int* __restrict__ deg) {
    int i = blockIdx.x * 256 + threadIdx.x;
    if (i < N_NODES) deg[i] = 0;
}

// 4 independent atomic chains per thread (latency-bound, not BW-bound)
__global__ __launch_bounds__(256) void k_count_deg(const int* __restrict__ col,
                                                   int* __restrict__ deg) {
    const int G = gridDim.x * 256;
    int e0 = blockIdx.x * 256 + threadIdx.x;
    int e1 = e0 + G, e2 = e1 + G, e3 = e2 + G;
    int c0 = (e0 < N_EDGES) ? col[e0] : -1;
    int c1 = (e1 < N_EDGES) ? col[e1] : -1;
    int c2 = (e2 < N_EDGES) ? col[e2] : -1;
    int c3 = (e3 < N_EDGES) ? col[e3] : -1;
    if (c0 >= 0) atomicAdd(&deg[c0], 1);
    if (c1 >= 0) atomicAdd(&deg[c1], 1);
    if (c2 >= 0) atomicAdd(&deg[c2], 1);
    if (c3 >= 0) atomicAdd(&deg[c3], 1);
}

__global__ __launch_bounds__(SCAN_BLK) void k_scan1(const int* __restrict__ deg,
                                                    int* __restrict__ rowptr,
                                                    int* __restrict__ bsum) {
    __shared__ int sc[SCAN_BLK];
    const int t = threadIdx.x;
    const int base = blockIdx.x * SCAN_TILE + t * SCAN_ITEMS;
    int v[SCAN_ITEMS];
    int tsum = 0;
#pragma unroll
    for (int j = 0; j < SCAN_ITEMS; ++j) {
        v[j] = (base + j < N_NODES) ? deg[base + j] : 0;
        tsum += v[j];
    }
    sc[t] = tsum;
    __syncthreads();
    for (int off = 1; off < SCAN_BLK; off <<= 1) {
        int x = (t >= off) ? sc[t - off] : 0;
        __syncthreads();
        sc[t] += x;
        __syncthreads();
    }
    int run = sc[t] - tsum;
#pragma unroll
    for (int j = 0; j < SCAN_ITEMS; ++j) {
        if (base + j < N_NODES) rowptr[base + j] = run;
        run += v[j];
    }
    if (t == SCAN_BLK - 1) bsum[blockIdx.x] = sc[SCAN_BLK - 1];
}

__global__ __launch_bounds__(SCAN_BLK) void k_scan2(int* __restrict__ bsum) {
    __shared__ int sc[SCAN_BLK];
    const int t = threadIdx.x;
    int v = (t < SCAN_NBLK) ? bsum[t] : 0;
    sc[t] = v;
    __syncthreads();
    for (int off = 1; off < SCAN_BLK; off <<= 1) {
        int x = (t >= off) ? sc[t - off] : 0;
        __syncthreads();
        sc[t] += x;
        __syncthreads();
    }
    if (t < SCAN_NBLK) bsum[t] = sc[t] - v;
}

__global__ __launch_bounds__(256) void k_scan3(int* __restrict__ rowptr,
                                               const int* __restrict__ bsum,
                                               int* __restrict__ cursor) {
    int i = blockIdx.x * 256 + threadIdx.x;
    if (i < N_NODES) {
        int r = rowptr[i] + bsum[i / SCAN_TILE];
        rowptr[i] = r;
        cursor[i] = r;
    }
    if (i == 0) rowptr[N_NODES] = N_EDGES;
}

__global__ __launch_bounds__(256) void k_dinv(const int* __restrict__ deg,
                                              float* __restrict__ dinv) {
    int i = blockIdx.x * 256 + threadIdx.x;
    if (i < N_NODES) dinv[i] = rsqrtf(1.0f + (float)deg[i]);   // +1 self-loop
}

// fill, XCD-range-partitioned (R7-proven, no nt)
__global__ __launch_bounds__(256) void k_fill(const int* __restrict__ row,
                                              const int* __restrict__ col,
                                              const float* __restrict__ dinv,
                                              int* __restrict__ cursor,
                                              int2* __restrict__ csr) {
    const int range = blockIdx.x & (FILL_RANGES - 1);
    const int lo = range * RANGE_SIZE;
    const int hi = lo + RANGE_SIZE;
    const int stride = (gridDim.x >> 3) * 256;
    for (int e = (blockIdx.x >> 3) * 256 + threadIdx.x; e < N_EDGES; e += stride) {
        int c = col[e];
        if (c >= lo && c < hi) {
            int r = row[e];
            int pos = atomicAdd(&cursor[c], 1);
            csr[pos] = make_int2(r, __float_as_int((1.0f - ALPHA) * dinv[r] * dinv[c]));
        }
    }
}

// ---------------- input GEMM: h_bf = h0_bf = bf16(relu(x@W0+b0)), chunked ----------------

__global__ __launch_bounds__(256) void k_gemm_in(const float* __restrict__ x,
                                                 const float* __restrict__ W0,
                                                 const float* __restrict__ b0,
                                                 ushortT* __restrict__ h_bf,
                                                 ushortT* __restrict__ h0_bf) {
    __shared__ float sW[N_FEATS * HIDDEN];   // 32 KB
    __shared__ float sX[64 * N_FEATS];       // 32 KB
    const int v0 = blockIdx.x * 64;
    const bool full = (v0 + 64 <= N_NODES);

    const float4* W4 = (const float4*)W0;
    for (int idx = threadIdx.x; idx < (N_FEATS * HIDDEN) / 4; idx += 256)
        ((float4*)sW)[idx] = W4[idx];
    if (full) {
        const float4* X4 = (const float4*)(x + (size_t)v0 * N_FEATS);
        for (int idx = threadIdx.x; idx < (64 * N_FEATS) / 4; idx += 256)
            ((float4*)sX)[idx] = X4[idx];
    } else {
        for (int idx = threadIdx.x; idx < 64 * N_FEATS; idx += 256) {
            int r = idx >> 7, k = idx & 127;
            int v = v0 + r;
            sX[idx] = (v < N_NODES) ? x[(size_t)v * N_FEATS + k] : 0.0f;
        }
    }
    __syncthreads();

    const int c  = threadIdx.x & 63;
    const int r0 = threadIdx.x >> 6;   // 0..3
    float acc[16];
#pragma unroll
    for (int j = 0; j < 16; ++j) acc[j] = 0.0f;

    for (int k = 0; k < N_FEATS; ++k) {
        float w = sW[k * HIDDEN + c];
#pragma unroll
        for (int j = 0; j < 16; ++j)
            acc[j] += sX[(r0 + 4 * j) * N_FEATS + k] * w;
    }

    const float bias = b0[c];
#pragma unroll
    for (int j = 0; j < 16; ++j) {
        int v = v0 + r0 + 4 * j;
        if (v < N_NODES) {
            ushortT val = f2bf(fmaxf(acc[j] + bias, 0.0f));
            size_t o = chunked_off(v, c);
            h_bf [o] = val;
            h0_bf[o] = val;
        }
    }
}

// ---------------- fused SpMM, feature-chunked ----------------
// chunk = blockIdx / SPMM_BPC (dispatch-order serialized -> 3.2MB gather plane
// is L2-resident per XCD). wave = one (node, chunk); 8-lane groups each fetch
// one edge's 32B chunk-row (8 edges per instruction, 2 rounds in flight).

__global__ __launch_bounds__(256) void k_spmm(const int* __restrict__ rowptr,
                                              const int2* __restrict__ csr,
                                              const float* __restrict__ dinv,
                                              const ushortT* __restrict__ h_bf,
                                              const ushortT* __restrict__ h0_bf,
                                              ushortT* __restrict__ buf_bf) {
    const int wv   = threadIdx.x >> 6;
    const int lane = threadIdx.x & 63;
    const int g    = lane >> 3;     // edge group 0..7
    const int fl   = lane & 7;      // feature pair slot
    const int chunk = blockIdx.x / SPMM_BPC;
    const int node  = (blockIdx.x % SPMM_BPC) * 4 + wv;
    if (node >= N_NODES) return;

    const ushortT* hC = h_bf + (size_t)chunk * N_NODES * CF;

    const int e0 = rowptr[node];
    const int e1 = rowptr[node + 1];

    float ax = 0.0f, ay = 0.0f;

    for (int eb = e0; eb < e1; eb += 64) {
        int n = e1 - eb;
        if (n > 64) n = 64;
        int   idx = 0;
        float w   = 0.0f;
        if (lane < n) {
            int2 e = csr[eb + lane];
            idx = e.x;
            w   = __int_as_float(e.y);
        }
        // lanes >= n hold (0, 0.0f); shfl from them contributes 0.
        for (int j = 0; j < n; j += 16) {
            int   s0 = __shfl(idx, j + g);
            int   s1 = __shfl(idx, j + 8 + g);
            float w0 = __shfl(w, j + g);
            float w1 = __shfl(w, j + 8 + g);
            uintT v0 = *(const uintT*)(hC + (size_t)s0 * CF + 2 * fl);
            uintT v1 = *(const uintT*)(hC + (size_t)s1 * CF + 2 * fl);
            ax += w0 * bf2f((ushortT)(v0 & 0xFFFFu));
            ay += w0 * bf2f((ushortT)(v0 >> 16));
            ax += w1 * bf2f((ushortT)(v1 & 0xFFFFu));
            ay += w1 * bf2f((ushortT)(v1 >> 16));
        }
    }

    // reduce across the 8 edge groups
    ax += __shfl_xor(ax, 8);  ay += __shfl_xor(ay, 8);
    ax += __shfl_xor(ax, 16); ay += __shfl_xor(ay, 16);
    ax += __shfl_xor(ax, 32); ay += __shfl_xor(ay, 32);

    if (g == 0) {
        const float d  = dinv[node];
        const float cs = (1.0f - ALPHA) * d * d;
        const size_t so = (size_t)chunk * N_NODES * CF + (size_t)node * CF + 2 * fl;
        uintT hv  = *(const uintT*)(h_bf  + so);
        uintT h0v = *(const uintT*)(h0_bf + so);
        float rx = cs * bf2f((ushortT)(hv & 0xFFFFu)) + ALPHA * bf2f((ushortT)(h0v & 0xFFFFu)) + ax;
        float ry = cs * bf2f((ushortT)(hv >> 16))     + ALPHA * bf2f((ushortT)(h0v >> 16))     + ay;
        ushort2 o; o.x = f2bf(rx); o.y = f2bf(ry);
        *(ushort2*)(buf_bf + so) = o;
    }
}

// ---------------- layer GEMM: h_bf = bf16(relu(beta*(S@W) + (1-beta)*S)), chunked ----------------

__global__ __launch_bounds__(256) void k_gemm_layer(const ushortT* __restrict__ S_bf,
                                                    const float* __restrict__ W,
                                                    float beta,
                                                    ushortT* __restrict__ hout_bf) {
    __shared__ float sW[HIDDEN * HIDDEN];   // 16 KB
    __shared__ float sS[64 * HIDDEN];       // 16 KB
    const int v0 = blockIdx.x * 64;
    const bool full = (v0 + 64 <= N_NODES);

    const float4* W4 = (const float4*)W;
    for (int idx = threadIdx.x; idx < (HIDDEN * HIDDEN) / 4; idx += 256)
        ((float4*)sW)[idx] = W4[idx];
    if (full) {
        // chunk-major staging: contiguous 2KB runs per chunk plane
        for (int idx = threadIdx.x; idx < 1024; idx += 256) {
            int chunk = idx >> 8;        // 0..3
            int rem   = idx & 255;
            int r     = rem >> 2;        // 0..63
            int slot  = rem & 3;         // 4 ushorts each
            ushort4 u = ((const ushort4*)(S_bf + ((size_t)chunk * N_NODES + v0 + r) * CF))[slot];
            int f = chunk * 16 + slot * 4;
            sS[r * HIDDEN + f + 0] = bf2f(u.x);
            sS[r * HIDDEN + f + 1] = bf2f(u.y);
            sS[r * HIDDEN + f + 2] = bf2f(u.z);
            sS[r * HIDDEN + f + 3] = bf2f(u.w);
        }
    } else {
        for (int idx = threadIdx.x; idx < 64 * HIDDEN; idx += 256) {
            int r = idx >> 6, k = idx & 63;
            int v = v0 + r;
            sS[idx] = (v < N_NODES) ? bf2f(S_bf[chunked_off(v, k)]) : 0.0f;
        }
    }
    __syncthreads();

    const int c  = threadIdx.x & 63;
    const int r0 = threadIdx.x >> 6;
    float acc[16];
#pragma unroll
    for (int j = 0; j < 16; ++j) acc[j] = 0.0f;

    for (int k = 0; k < HIDDEN; ++k) {
        float w = sW[k * HIDDEN + c];
#pragma unroll
        for (int j = 0; j < 16; ++j)
            acc[j] += sS[(r0 + 4 * j) * HIDDEN + k] * w;
    }

#pragma unroll
    for (int j = 0; j < 16; ++j) {
        int r = r0 + 4 * j;
        int v = v0 + r;
        if (v < N_NODES) {
            float s   = sS[r * HIDDEN + c];
            float val = fmaxf(beta * acc[j] + (1.0f - beta) * s, 0.0f);
            hout_bf[chunked_off(v, c)] = f2bf(val);
        }
    }
}

// ---------------- output GEMM: out = h @ W_out + b_out (h chunked bf16) ----------------

__global__ __launch_bounds__(256) void k_gemm_out(const ushortT* __restrict__ h_bf,
                                                  const float* __restrict__ Wout,
                                                  const float* __restrict__ bout,
                                                  float* __restrict__ out) {
    __shared__ float sW[HIDDEN * N_CLASSES];  // 10 KB
    __shared__ float sH[64 * HIDDEN];         // 16 KB
    const int v0 = blockIdx.x * 64;
    const bool full = (v0 + 64 <= N_NODES);

    for (int idx = threadIdx.x; idx < HIDDEN * N_CLASSES; idx += 256)
        sW[idx] = Wout[idx];
    if (full) {
        for (int idx = threadIdx.x; idx < 1024; idx += 256) {
            int chunk = idx >> 8;
            int rem   = idx & 255;
            int r     = rem >> 2;
            int slot  = rem & 3;
            ushort4 u = ((const ushort4*)(h_bf + ((size_t)chunk * N_NODES + v0 + r) * CF))[slot];
            int f = chunk * 16 + slot * 4;
            sH[r * HIDDEN + f + 0] = bf2f(u.x);
            sH[r * HIDDEN + f + 1] = bf2f(u.y);
            sH[r * HIDDEN + f + 2] = bf2f(u.z);
            sH[r * HIDDEN + f + 3] = bf2f(u.w);
        }
    } else {
        for (int idx = threadIdx.x; idx < 64 * HIDDEN; idx += 256) {
            int r = idx >> 6, k = idx & 63;
            int v = v0 + r;
            sH[idx] = (v < N_NODES) ? bf2f(h_bf[chunked_off(v, k)]) : 0.0f;
        }
    }
    __syncthreads();

    for (int idx = threadIdx.x; idx < 64 * N_CLASSES; idx += 256) {
        int r = idx / N_CLASSES, c = idx % N_CLASSES;
        int v = v0 + r;
        if (v < N_NODES) {
            float acc = bout[c];
#pragma unroll 8
            for (int k = 0; k < HIDDEN; ++k)
                acc += sH[r * HIDDEN + k] * sW[k * N_CLASSES + c];
            out[(size_t)v * N_CLASSES + c] = acc;
        }
    }
}

// ---------------- launch ----------------

extern "C" void kernel_launch(void* const* d_in, const int* in_sizes, int n_in,
                              void* d_out, int out_size, void* d_ws, size_t ws_size,
                              hipStream_t stream) {
    const float* x    = (const float*)d_in[0];
    const int*   ei   = (const int*)d_in[1];
    const float* W0   = (const float*)d_in[2];
    const float* b0   = (const float*)d_in[3];
    const float* Wl   = (const float*)d_in[4];
    const float* Wout = (const float*)d_in[5];
    const float* bout = (const float*)d_in[6];
    float* out = (float*)d_out;

    const int* row = ei;             // edge_index[0] = source
    const int* col = ei + N_EDGES;   // edge_index[1] = target

    char* ws = (char*)d_ws;
    size_t off = 0;
    auto alloc = [&](size_t bytes) -> void* {
        void* p = ws + off;
        off += (bytes + 255) & ~(size_t)255;
        return p;
    };
    int*     deg    = (int*)alloc((size_t)N_NODES * 4);
    int*     rowptr = (int*)alloc((size_t)(N_NODES + 1) * 4);
    int*     cursor = (int*)alloc((size_t)N_NODES * 4);
    int*     bsum   = (int*)alloc((size_t)SCAN_NBLK * 4);
    int2*    csr    = (int2*)alloc((size_t)N_EDGES * 8);
    float*   dinv   = (float*)alloc((size_t)N_NODES * 4);
    ushortT* h0_bf  = (ushortT*)alloc((size_t)N_NODES * HIDDEN * 2);
    ushortT* buf_bf = (ushortT*)alloc((size_t)N_NODES * HIDDEN * 2);
    ushortT* h_bf   = (ushortT*)alloc((size_t)N_NODES * HIDDEN * 2);

    const int gN   = (N_NODES + 255) / 256;
    const int gRow = (N_NODES + 63) / 64;
    const int gSpm = CHUNKS * SPMM_BPC;                    // 100000 blocks
    const int gE4  = (N_EDGES + 4 * 256 - 1) / (4 * 256);  // 4 edges per thread

    // CSR build (by target node)
    k_zero_deg <<<gN, 256, 0, stream>>>(deg);
    k_count_deg<<<gE4, 256, 0, stream>>>(col, deg);
    k_scan1    <<<SCAN_NBLK, SCAN_BLK, 0, stream>>>(deg, rowptr, bsum);
    k_scan2    <<<1, SCAN_BLK, 0, stream>>>(bsum);
    k_scan3    <<<gN, 256, 0, stream>>>(rowptr, bsum, cursor);
    k_dinv     <<<gN, 256, 0, stream>>>(deg, dinv);
    k_fill     <<<FILL_BLOCKS, 256, 0, stream>>>(row, col, dinv, cursor, csr);

    // h = relu(x@W0 + b0) -> h_bf, h0_bf (chunked)
    k_gemm_in<<<gRow, 256, 0, stream>>>(x, W0, b0, h_bf, h0_bf);

    for (int i = 0; i < N_LAYERS; ++i) {
        float beta = logf(LAMDA / (float)(i + 1) + 1.0f);
        // buf = (1-a)*A_hat*h + a*h0   (chunked gather, f32 accumulate)
        k_spmm<<<gSpm, 256, 0, stream>>>(rowptr, csr, dinv, h_bf, h0_bf, buf_bf);
        // h_bf = bf16(relu(beta*(buf@Wl[i]) + (1-beta)*buf))
        k_gemm_layer<<<gRow, 256, 0, stream>>>(buf_bf, Wl + (size_t)i * HIDDEN * HIDDEN,
                                               beta, h_bf);
    }

    // out = h @ W_out + b_out
    k_gemm_out<<<gRow, 256, 0, stream>>>(h_bf, Wout, bout, out);
}

// Round 10
// 849.084 us; speedup vs baseline: 1.6481x; 1.6481x over previous
//
#include <hip/hip_runtime.h>
#include <cmath>

#define N_NODES   100000
#define N_EDGES   1600000
#define N_FEATS   128
#define HIDDEN    64
#define N_CLASSES 40
#define N_LAYERS  8
#define ALPHA     0.1f
#define LAMDA     0.5f

#define SCAN_ITEMS 8
#define SCAN_BLK   256
#define SCAN_TILE  (SCAN_ITEMS * SCAN_BLK)                  // 2048
#define SCAN_NBLK  ((N_NODES + SCAN_TILE - 1) / SCAN_TILE)  // 49

#define FILL_RANGES 8
#define RANGE_SIZE  ((N_NODES + FILL_RANGES - 1) / FILL_RANGES)  // 12500
#define FILL_BLOCKS 1024

typedef unsigned short ushortT;
typedef unsigned int   uintT;

__device__ __forceinline__ float bf2f(ushortT u) {
    return __uint_as_float(((uintT)u) << 16);
}
__device__ __forceinline__ float bflo(uintT u) {            // low bf16 of a packed pair
    return __uint_as_float(u << 16);
}
__device__ __forceinline__ float bfhi(uintT u) {            // high bf16 of a packed pair
    return __uint_as_float(u & 0xFFFF0000u);
}
__device__ __forceinline__ ushortT f2bf(float f) {
    uintT x = __float_as_uint(f);
    return (ushortT)((x + 0x7FFFu + ((x >> 16) & 1u)) >> 16);   // RNE
}

// ---------------- CSR build ----------------

__global__ __launch_bounds__(256) void k_zero_deg(int* __restrict__ deg) {
    int i = blockIdx.x * 256 + threadIdx.x;
    if (i < N_NODES) deg[i] = 0;
}

// 4 independent atomic chains per thread (latency-bound, not BW-bound)
__global__ __launch_bounds__(256) void k_count_deg(const int* __restrict__ col,
                                                   int* __restrict__ deg) {
    const int G = gridDim.x * 256;
    int e0 = blockIdx.x * 256 + threadIdx.x;
    int e1 = e0 + G, e2 = e1 + G, e3 = e2 + G;
    int c0 = (e0 < N_EDGES) ? col[e0] : -1;
    int c1 = (e1 < N_EDGES) ? col[e1] : -1;
    int c2 = (e2 < N_EDGES) ? col[e2] : -1;
    int c3 = (e3 < N_EDGES) ? col[e3] : -1;
    if (c0 >= 0) atomicAdd(&deg[c0], 1);
    if (c1 >= 0) atomicAdd(&deg[c1], 1);
    if (c2 >= 0) atomicAdd(&deg[c2], 1);
    if (c3 >= 0) atomicAdd(&deg[c3], 1);
}

__global__ __launch_bounds__(SCAN_BLK) void k_scan1(const int* __restrict__ deg,
                                                    int* __restrict__ rowptr,
                                                    int* __restrict__ bsum) {
    __shared__ int sc[SCAN_BLK];
    const int t = threadIdx.x;
    const int base = blockIdx.x * SCAN_TILE + t * SCAN_ITEMS;
    int v[SCAN_ITEMS];
    int tsum = 0;
#pragma unroll
    for (int j = 0; j < SCAN_ITEMS; ++j) {
        v[j] = (base + j < N_NODES) ? deg[base + j] : 0;
        tsum += v[j];
    }
    sc[t] = tsum;
    __syncthreads();
    for (int off = 1; off < SCAN_BLK; off <<= 1) {
        int x = (t >= off) ? sc[t - off] : 0;
        __syncthreads();
        sc[t] += x;
        __syncthreads();
    }
    int run = sc[t] - tsum;
#pragma unroll
    for (int j = 0; j < SCAN_ITEMS; ++j) {
        if (base + j < N_NODES) rowptr[base + j] = run;
        run += v[j];
    }
    if (t == SCAN_BLK - 1) bsum[blockIdx.x] = sc[SCAN_BLK - 1];
}

__global__ __launch_bounds__(SCAN_BLK) void k_scan2(int* __restrict__ bsum) {
    __shared__ int sc[SCAN_BLK];
    const int t = threadIdx.x;
    int v = (t < SCAN_NBLK) ? bsum[t] : 0;
    sc[t] = v;
    __syncthreads();
    for (int off = 1; off < SCAN_BLK; off <<= 1) {
        int x = (t >= off) ? sc[t - off] : 0;
        __syncthreads();
        sc[t] += x;
        __syncthreads();
    }
    if (t < SCAN_NBLK) bsum[t] = sc[t] - v;
}

__global__ __launch_bounds__(256) void k_scan3(int* __restrict__ rowptr,
                                               const int* __restrict__ bsum,
                                               int* __restrict__ cursor) {
    int i = blockIdx.x * 256 + threadIdx.x;
    if (i < N_NODES) {
        int r = rowptr[i] + bsum[i / SCAN_TILE];
        rowptr[i] = r;
        cursor[i] = r;
    }
    if (i == 0) rowptr[N_NODES] = N_EDGES;
}

__global__ __launch_bounds__(256) void k_dinv(const int* __restrict__ deg,
                                              float* __restrict__ dinv) {
    int i = blockIdx.x * 256 + threadIdx.x;
    if (i < N_NODES) dinv[i] = rsqrtf(1.0f + (float)deg[i]);   // +1 self-loop
}

// fill, XCD-range-partitioned (R7-proven, no nt)
__global__ __launch_bounds__(256) void k_fill(const int* __restrict__ row,
                                              const int* __restrict__ col,
                                              const float* __restrict__ dinv,
                                              int* __restrict__ cursor,
                                              int2* __restrict__ csr) {
    const int range = blockIdx.x & (FILL_RANGES - 1);
    const int lo = range * RANGE_SIZE;
    const int hi = lo + RANGE_SIZE;
    const int stride = (gridDim.x >> 3) * 256;
    for (int e = (blockIdx.x >> 3) * 256 + threadIdx.x; e < N_EDGES; e += stride) {
        int c = col[e];
        if (c >= lo && c < hi) {
            int r = row[e];
            int pos = atomicAdd(&cursor[c], 1);
            csr[pos] = make_int2(r, __float_as_int((1.0f - ALPHA) * dinv[r] * dinv[c]));
        }
    }
}

// ---------------- input GEMM: h_bf = h0_bf = bf16(relu(x@W0+b0)) ----------------

__global__ __launch_bounds__(256) void k_gemm_in(const float* __restrict__ x,
                                                 const float* __restrict__ W0,
                                                 const float* __restrict__ b0,
                                                 ushortT* __restrict__ h_bf,
                                                 ushortT* __restrict__ h0_bf) {
    __shared__ float sW[N_FEATS * HIDDEN];   // 32 KB
    __shared__ float sX[64 * N_FEATS];       // 32 KB
    const int v0 = blockIdx.x * 64;
    const bool full = (v0 + 64 <= N_NODES);

    const float4* W4 = (const float4*)W0;
    for (int idx = threadIdx.x; idx < (N_FEATS * HIDDEN) / 4; idx += 256)
        ((float4*)sW)[idx] = W4[idx];
    if (full) {
        const float4* X4 = (const float4*)(x + (size_t)v0 * N_FEATS);
        for (int idx = threadIdx.x; idx < (64 * N_FEATS) / 4; idx += 256)
            ((float4*)sX)[idx] = X4[idx];
    } else {
        for (int idx = threadIdx.x; idx < 64 * N_FEATS; idx += 256) {
            int r = idx >> 7, k = idx & 127;
            int v = v0 + r;
            sX[idx] = (v < N_NODES) ? x[(size_t)v * N_FEATS + k] : 0.0f;
        }
    }
    __syncthreads();

    const int c  = threadIdx.x & 63;
    const int r0 = threadIdx.x >> 6;   // 0..3
    float acc[16];
#pragma unroll
    for (int j = 0; j < 16; ++j) acc[j] = 0.0f;

    for (int k = 0; k < N_FEATS; ++k) {
        float w = sW[k * HIDDEN + c];
#pragma unroll
        for (int j = 0; j < 16; ++j)
            acc[j] += sX[(r0 + 4 * j) * N_FEATS + k] * w;
    }

    const float bias = b0[c];
#pragma unroll
    for (int j = 0; j < 16; ++j) {
        int v = v0 + r0 + 4 * j;
        if (v < N_NODES) {
            ushortT val = f2bf(fmaxf(acc[j] + bias, 0.0f));
            h_bf [(size_t)v * HIDDEN + c] = val;
            h0_bf[(size_t)v * HIDDEN + c] = val;
        }
    }
}

// ---------------- fused SpMM: buf_bf = bf16((1-a)*A_hat*h + a*h0) ----------------
// one wave per node; 8 groups of 8 lanes; each group fetches one edge-row as
// 8 x 16B uint4 loads (8 requests per 128B row, vs 32 before); 16 edges in
// flight per wave (2 unrolled rounds). Cross-group combine via 3 shfl_xor.

__global__ __launch_bounds__(256) void k_spmm(const int* __restrict__ rowptr,
                                              const int2* __restrict__ csr,
                                              const float* __restrict__ dinv,
                                              const ushortT* __restrict__ h_bf,
                                              const ushortT* __restrict__ h0_bf,
                                              ushortT* __restrict__ buf_bf) {
    const int lane = threadIdx.x & 63;
    const int g    = lane >> 3;     // edge slot 0..7
    const int fl   = lane & 7;      // feature octet: features [8*fl, 8*fl+8)
    const int node = (blockIdx.x * 256 + threadIdx.x) >> 6;
    if (node >= N_NODES) return;

    const int e0 = rowptr[node];
    const int e1 = rowptr[node + 1];

    float acc[8];
#pragma unroll
    for (int i = 0; i < 8; ++i) acc[i] = 0.0f;

#define FMA8(V, WGT)                                     \
    do {                                                 \
        acc[0] += (WGT) * bflo((V).x);                   \
        acc[1] += (WGT) * bfhi((V).x);                   \
        acc[2] += (WGT) * bflo((V).y);                   \
        acc[3] += (WGT) * bfhi((V).y);                   \
        acc[4] += (WGT) * bflo((V).z);                   \
        acc[5] += (WGT) * bfhi((V).z);                   \
        acc[6] += (WGT) * bflo((V).w);                   \
        acc[7] += (WGT) * bfhi((V).w);                   \
    } while (0)

    for (int eb = e0; eb < e1; eb += 64) {
        int n = e1 - eb;
        if (n > 64) n = 64;
        int   idx = 0;
        float w   = 0.0f;
        if (lane < n) {
            int2 e = csr[eb + lane];
            idx = e.x;
            w   = __int_as_float(e.y);
        }
        // lanes >= n hold (0, 0.0f); shfl from them contributes 0 safely.
        for (int j = 0; j < n; j += 16) {
            int   s0 = __shfl(idx, j + g);
            int   s1 = __shfl(idx, j + 8 + g);
            float w0 = __shfl(w, j + g);
            float w1 = __shfl(w, j + 8 + g);
            uint4 v0 = *(const uint4*)(h_bf + (size_t)s0 * HIDDEN + 8 * fl);
            uint4 v1 = *(const uint4*)(h_bf + (size_t)s1 * HIDDEN + 8 * fl);
            FMA8(v0, w0);
            FMA8(v1, w1);
        }
    }

    // combine the 8 edge groups: every lane ends with the full sum for its octet
#pragma unroll
    for (int i = 0; i < 8; ++i) acc[i] += __shfl_xor(acc[i], 8);
#pragma unroll
    for (int i = 0; i < 8; ++i) acc[i] += __shfl_xor(acc[i], 16);
#pragma unroll
    for (int i = 0; i < 8; ++i) acc[i] += __shfl_xor(acc[i], 32);

    if (g == 0) {   // lanes 0..7: add self-loop + residual, pack, write 128B row
        const float d  = dinv[node];
        const float cs = (1.0f - ALPHA) * d * d;
        const size_t so = (size_t)node * HIDDEN + 8 * fl;
        uint4 hv  = *(const uint4*)(h_bf  + so);
        uint4 h0v = *(const uint4*)(h0_bf + so);
        acc[0] += cs * bflo(hv.x) + ALPHA * bflo(h0v.x);
        acc[1] += cs * bfhi(hv.x) + ALPHA * bfhi(h0v.x);
        acc[2] += cs * bflo(hv.y) + ALPHA * bflo(h0v.y);
        acc[3] += cs * bfhi(hv.y) + ALPHA * bfhi(h0v.y);
        acc[4] += cs * bflo(hv.z) + ALPHA * bflo(h0v.z);
        acc[5] += cs * bfhi(hv.z) + ALPHA * bfhi(h0v.z);
        acc[6] += cs * bflo(hv.w) + ALPHA * bflo(h0v.w);
        acc[7] += cs * bfhi(hv.w) + ALPHA * bfhi(h0v.w);
        uint4 o;
        o.x = ((uintT)f2bf(acc[1]) << 16) | f2bf(acc[0]);
        o.y = ((uintT)f2bf(acc[3]) << 16) | f2bf(acc[2]);
        o.z = ((uintT)f2bf(acc[5]) << 16) | f2bf(acc[4]);
        o.w = ((uintT)f2bf(acc[7]) << 16) | f2bf(acc[6]);
        *(uint4*)(buf_bf + so) = o;
    }
#undef FMA8
}

// ---------------- layer GEMM: h_bf = bf16(relu(beta*(S@W) + (1-beta)*S)) ----------------

__global__ __launch_bounds__(256) void k_gemm_layer(const ushortT* __restrict__ S_bf,
                                                    const float* __restrict__ W,
                                                    float beta,
                                                    ushortT* __restrict__ hout_bf) {
    __shared__ float sW[HIDDEN * HIDDEN];   // 16 KB
    __shared__ float sS[64 * HIDDEN];       // 16 KB
    const int v0 = blockIdx.x * 64;
    const bool full = (v0 + 64 <= N_NODES);

    const float4* W4 = (const float4*)W;
    for (int idx = threadIdx.x; idx < (HIDDEN * HIDDEN) / 4; idx += 256)
        ((float4*)sW)[idx] = W4[idx];
    if (full) {
        const ushort4* S4 = (const ushort4*)(S_bf + (size_t)v0 * HIDDEN);
        for (int idx = threadIdx.x; idx < (64 * HIDDEN) / 4; idx += 256) {
            ushort4 u = S4[idx];
            sS[idx * 4 + 0] = bf2f(u.x);
            sS[idx * 4 + 1] = bf2f(u.y);
            sS[idx * 4 + 2] = bf2f(u.z);
            sS[idx * 4 + 3] = bf2f(u.w);
        }
    } else {
        for (int idx = threadIdx.x; idx < 64 * HIDDEN; idx += 256) {
            int r = idx >> 6, k = idx & 63;
            int v = v0 + r;
            sS[idx] = (v < N_NODES) ? bf2f(S_bf[(size_t)v * HIDDEN + k]) : 0.0f;
        }
    }
    __syncthreads();

    const int c  = threadIdx.x & 63;
    const int r0 = threadIdx.x >> 6;
    float acc[16];
#pragma unroll
    for (int j = 0; j < 16; ++j) acc[j] = 0.0f;

    for (int k = 0; k < HIDDEN; ++k) {
        float w = sW[k * HIDDEN + c];
#pragma unroll
        for (int j = 0; j < 16; ++j)
            acc[j] += sS[(r0 + 4 * j) * HIDDEN + k] * w;
    }

#pragma unroll
    for (int j = 0; j < 16; ++j) {
        int r = r0 + 4 * j;
        int v = v0 + r;
        if (v < N_NODES) {
            float s   = sS[r * HIDDEN + c];
            float val = fmaxf(beta * acc[j] + (1.0f - beta) * s, 0.0f);
            hout_bf[(size_t)v * HIDDEN + c] = f2bf(val);
        }
    }
}

// ---------------- output GEMM: out = h @ W_out + b_out (h in bf16) ----------------

__global__ __launch_bounds__(256) void k_gemm_out(const ushortT* __restrict__ h_bf,
                                                  const float* __restrict__ Wout,
                                                  const float* __restrict__ bout,
                                                  float* __restrict__ out) {
    __shared__ float sW[HIDDEN * N_CLASSES];  // 10 KB
    __shared__ float sH[64 * HIDDEN];         // 16 KB
    const int v0 = blockIdx.x * 64;
    const bool full = (v0 + 64 <= N_NODES);

    for (int idx = threadIdx.x; idx < HIDDEN * N_CLASSES; idx += 256)
        sW[idx] = Wout[idx];
    if (full) {
        const ushort4* H4 = (const ushort4*)(h_bf + (size_t)v0 * HIDDEN);
        for (int idx = threadIdx.x; idx < (64 * HIDDEN) / 4; idx += 256) {
            ushort4 u = H4[idx];
            sH[idx * 4 + 0] = bf2f(u.x);
            sH[idx * 4 + 1] = bf2f(u.y);
            sH[idx * 4 + 2] = bf2f(u.z);
            sH[idx * 4 + 3] = bf2f(u.w);
        }
    } else {
        for (int idx = threadIdx.x; idx < 64 * HIDDEN; idx += 256) {
            int r = idx >> 6, k = idx & 63;
            int v = v0 + r;
            sH[idx] = (v < N_NODES) ? bf2f(h_bf[(size_t)v * HIDDEN + k]) : 0.0f;
        }
    }
    __syncthreads();

    for (int idx = threadIdx.x; idx < 64 * N_CLASSES; idx += 256) {
        int r = idx / N_CLASSES, c = idx % N_CLASSES;
        int v = v0 + r;
        if (v < N_NODES) {
            float acc = bout[c];
#pragma unroll 8
            for (int k = 0; k < HIDDEN; ++k)
                acc += sH[r * HIDDEN + k] * sW[k * N_CLASSES + c];
            out[(size_t)v * N_CLASSES + c] = acc;
        }
    }
}

// ---------------- launch ----------------

extern "C" void kernel_launch(void* const* d_in, const int* in_sizes, int n_in,
                              void* d_out, int out_size, void* d_ws, size_t ws_size,
                              hipStream_t stream) {
    const float* x    = (const float*)d_in[0];
    const int*   ei   = (const int*)d_in[1];
    const float* W0   = (const float*)d_in[2];
    const float* b0   = (const float*)d_in[3];
    const float* Wl   = (const float*)d_in[4];
    const float* Wout = (const float*)d_in[5];
    const float* bout = (const float*)d_in[6];
    float* out = (float*)d_out;

    const int* row = ei;             // edge_index[0] = source
    const int* col = ei + N_EDGES;   // edge_index[1] = target

    char* ws = (char*)d_ws;
    size_t off = 0;
    auto alloc = [&](size_t bytes) -> void* {
        void* p = ws + off;
        off += (bytes + 255) & ~(size_t)255;
        return p;
    };
    int*     deg    = (int*)alloc((size_t)N_NODES * 4);
    int*     rowptr = (int*)alloc((size_t)(N_NODES + 1) * 4);
    int*     cursor = (int*)alloc((size_t)N_NODES * 4);
    int*     bsum   = (int*)alloc((size_t)SCAN_NBLK * 4);
    int2*    csr    = (int2*)alloc((size_t)N_EDGES * 8);
    float*   dinv   = (float*)alloc((size_t)N_NODES * 4);
    ushortT* h0_bf  = (ushortT*)alloc((size_t)N_NODES * HIDDEN * 2);
    ushortT* buf_bf = (ushortT*)alloc((size_t)N_NODES * HIDDEN * 2);
    ushortT* h_bf   = (ushortT*)alloc((size_t)N_NODES * HIDDEN * 2);

    const int gN   = (N_NODES + 255) / 256;
    const int gRow = (N_NODES + 63) / 64;
    const int gSpm = (N_NODES * 64 + 255) / 256;           // wave per node
    const int gE4  = (N_EDGES + 4 * 256 - 1) / (4 * 256);  // 4 edges per thread

    // CSR build (by target node)
    k_zero_deg <<<gN, 256, 0, stream>>>(deg);
    k_count_deg<<<gE4, 256, 0, stream>>>(col, deg);
    k_scan1    <<<SCAN_NBLK, SCAN_BLK, 0, stream>>>(deg, rowptr, bsum);
    k_scan2    <<<1, SCAN_BLK, 0, stream>>>(bsum);
    k_scan3    <<<gN, 256, 0, stream>>>(rowptr, bsum, cursor);
    k_dinv     <<<gN, 256, 0, stream>>>(deg, dinv);
    k_fill     <<<FILL_BLOCKS, 256, 0, stream>>>(row, col, dinv, cursor, csr);

    // h = relu(x@W0 + b0) -> h_bf, h0_bf
    k_gemm_in<<<gRow, 256, 0, stream>>>(x, W0, b0, h_bf, h0_bf);

    for (int i = 0; i < N_LAYERS; ++i) {
        float beta = logf(LAMDA / (float)(i + 1) + 1.0f);
        // buf = (1-a)*A_hat*h + a*h0   (bf16 gather, f32 accumulate, bf16 out)
        k_spmm<<<gSpm, 256, 0, stream>>>(rowptr, csr, dinv, h_bf, h0_bf, buf_bf);
        // h_bf = bf16(relu(beta*(buf@Wl[i]) + (1-beta)*buf))
        k_gemm_layer<<<gRow, 256, 0, stream>>>(buf_bf, Wl + (size_t)i * HIDDEN * HIDDEN,
                                               beta, h_bf);
    }

    // out = h @ W_out + b_out
    k_gemm_out<<<gRow, 256, 0, stream>>>(h_bf, Wout, bout, out);
}